// Round 1
// baseline (249.092 us; speedup 1.0000x reference)
//
#include <hip/hip_runtime.h>
#include <math.h>

#define NB 4
#define NC 4
#define NF 257
#define NFR 1024
#define NTOT (NB * NC * NF * NFR)
#define NBC (NB * NC)
#define EPSV 1e-3f
#define EPS_MODEL 1e-5f
#define NCHUNK 32

typedef float v2f __attribute__((ext_vector_type(2)));

// Module-scope scratch: allocated at load, graph-capture safe, fully
// rewritten every call.
__device__ float g_Spart[NCHUNK * NBC * NFR];  // partial column sums
__device__ float g_S[NBC * NFR];               // S[b,c,n] = sum_f |X[b,c,f,n]|^2
__device__ float g_gP[96];                     // g_e, P_e per (b,c), e=0..2

// Wave-wide sum via DPP (VALU pipe, no LDS traffic). Lane 63 holds the sum.
__device__ __forceinline__ float dpp_red_sum(float v) {
  v += __int_as_float(__builtin_amdgcn_update_dpp(0, __float_as_int(v), 0x111, 0xf, 0xf, true)); // row_shr:1
  v += __int_as_float(__builtin_amdgcn_update_dpp(0, __float_as_int(v), 0x112, 0xf, 0xf, true)); // row_shr:2
  v += __int_as_float(__builtin_amdgcn_update_dpp(0, __float_as_int(v), 0x114, 0xf, 0xf, true)); // row_shr:4
  v += __int_as_float(__builtin_amdgcn_update_dpp(0, __float_as_int(v), 0x118, 0xf, 0xf, true)); // row_shr:8
  v += __int_as_float(__builtin_amdgcn_update_dpp(0, __float_as_int(v), 0x142, 0xa, 0xf, true)); // row_bcast:15
  v += __int_as_float(__builtin_amdgcn_update_dpp(0, __float_as_int(v), 0x143, 0xc, 0xf, true)); // row_bcast:31
  return v;
}

// ---------------------------------------------------------------------------
// K1: partial column sums, float4-vectorized, 512 blocks (full GPU).
// ---------------------------------------------------------------------------
__global__ __launch_bounds__(256) void k_colsum(const float* __restrict__ Xr,
                                                const float* __restrict__ Xi) {
  int u = blockIdx.x * 256 + threadIdx.x;  // bc*256 + q
  int fc = blockIdx.y;
  int f0 = fc * 9;
  int f1 = f0 + 9; if (f1 > NF) f1 = NF;
  int bc = u >> 8, q = u & 255;
  float4 s = make_float4(0.f, 0.f, 0.f, 0.f);
  for (int f = f0; f < f1; ++f) {
    float4 a = reinterpret_cast<const float4*>(Xr + (bc * NF + f) * NFR)[q];
    float4 b = reinterpret_cast<const float4*>(Xi + (bc * NF + f) * NFR)[q];
    s.x += a.x * a.x + b.x * b.x;
    s.y += a.y * a.y + b.y * b.y;
    s.z += a.z * a.z + b.z * b.z;
    s.w += a.w * a.w + b.w * b.w;
  }
  reinterpret_cast<float4*>(g_Spart + fc * (NBC * NFR) + bc * NFR)[q] = s;
}

// ---------------------------------------------------------------------------
// K2 (fused): reduce 32 partials -> g_S; block-reduce to s0; g_e/P_e table.
// ---------------------------------------------------------------------------
__global__ __launch_bounds__(256) void k_redgp() {
  int bc = blockIdx.x, tid = threadIdx.x;
  float4 s = make_float4(0.f, 0.f, 0.f, 0.f);
#pragma unroll
  for (int fc = 0; fc < NCHUNK; ++fc) {
    float4 a = reinterpret_cast<const float4*>(g_Spart + fc * (NBC * NFR) + bc * NFR)[tid];
    s.x += a.x; s.y += a.y; s.z += a.z; s.w += a.w;
  }
  reinterpret_cast<float4*>(g_S + bc * NFR)[tid] = s;
  float p = dpp_red_sum(s.x + s.y + s.z + s.w);
  __shared__ float r[4];
  if ((tid & 63) == 63) r[tid >> 6] = p;
  __syncthreads();
  if (tid == 0) {
    float s0 = (r[0] + r[1] + r[2] + r[3]) / (float)(NF * NFR);
    float P = 1.f;
#pragma unroll
    for (int e = 0; e < 3; ++e) {
      float g = fmaxf(s0 / P, 1e-5f);
      g_gP[e * 32 + bc] = g;
      g_gP[e * 32 + 16 + bc] = P;
      P *= g;
    }
  }
}

// Block-level reduction of 12 partials, 4-wave version: DPP within wave,
// one barrier, b128 LDS round-trip, double-buffered via `buf`.
__device__ __forceinline__ void block_reduce12(float* __restrict__ p,
                                               float (*red)[4][12], int buf,
                                               int lane, int wvid,
                                               float* __restrict__ s) {
#pragma unroll
  for (int k = 0; k < 12; ++k) p[k] = dpp_red_sum(p[k]);
  if (lane == 63) {
    float4* dst = reinterpret_cast<float4*>(&red[buf][wvid][0]);
    dst[0] = make_float4(p[0], p[1], p[2], p[3]);
    dst[1] = make_float4(p[4], p[5], p[6], p[7]);
    dst[2] = make_float4(p[8], p[9], p[10], p[11]);
  }
  __syncthreads();
  const float4* r = reinterpret_cast<const float4*>(&red[buf][0][0]);
#pragma unroll
  for (int k = 0; k < 3; ++k) {
    float4 a = r[k], b = r[3 + k], c = r[6 + k], d = r[9 + k];
    s[4 * k + 0] = a.x + b.x + c.x + d.x;
    s[4 * k + 1] = a.y + b.y + c.y + d.y;
    s[4 * k + 2] = a.z + b.z + c.z + d.z;
    s[4 * k + 3] = a.w + b.w + c.w + d.w;
  }
}

// ---------------------------------------------------------------------------
// Main: one block per (b,f), 256 threads (4 waves), 4 frames/thread held as
// 2x v2f (<2 x float>) pairs -> v_pk_fma_f32 codegen for accumulate/update.
// 4 waves/block doubles resident waves/CU (grid is fixed at 1028 blocks, so
// occupancy only grows via waves/block): 8 -> 16 waves/CU, hiding the
// DPP-chain + barrier latency of the 36 serial sweep stages.
// (256,4) bounds (VGPR cap 128; xc state is 32 VGPRs at 4 frames/thread).
// ---------------------------------------------------------------------------
__global__ __launch_bounds__(256, 4) void k_main(const float* __restrict__ Xr,
                                                 const float* __restrict__ Xi,
                                                 float* __restrict__ out, int nout) {
  const int blk = blockIdx.x;
  const int b = blk / NF, f = blk % NF;
  const int tid = threadIdx.x;            // 0..255
  const int lane = tid & 63, wvid = tid >> 6;
  const float invN = 1.f / (float)NFR;

  __shared__ float red[2][4][12];
  __shared__ float Wre[NC][NC], Wim[NC][NC];
  __shared__ float abc[8];

  v2f xcr[NC][2], xci[NC][2];
  int rowbase[NC];
#pragma unroll
  for (int c = 0; c < NC; ++c) {
    rowbase[c] = ((b * NC + c) * NF + f) * NFR;
    const float4* pr = reinterpret_cast<const float4*>(Xr + rowbase[c]);
    const float4* pi = reinterpret_cast<const float4*>(Xi + rowbase[c]);
    float4 a0 = pr[tid];
    float4 b0 = pi[tid];
    xcr[c][0] = (v2f){a0.x, a0.y}; xcr[c][1] = (v2f){a0.z, a0.w};
    xci[c][0] = (v2f){b0.x, b0.y}; xci[c][1] = (v2f){b0.z, b0.w};
  }
  if (tid < 16) {
    Wre[tid >> 2][tid & 3] = ((tid >> 2) == (tid & 3)) ? 1.f : 0.f;
    Wim[tid >> 2][tid & 3] = 0.f;
  }
  // W-init visibility to thread 0: ordered by the first sweep's barrier.

  v2f w2[NC][2];
  int buf = 0;

  for (int e = 0; e < 3; ++e) {
    // ---- per-epoch weights: w = g * rcp(max(2*sqrt(S/P), eps)) ----
#pragma unroll
    for (int c = 0; c < NC; ++c) {
      float g = g_gP[e * 32 + b * NC + c];
      float P = g_gP[e * 32 + 16 + b * NC + c];
      float sc = __builtin_amdgcn_rcpf(P);
      const float4* ps = reinterpret_cast<const float4*>(g_S + (b * NC + c) * NFR);
      float4 S0 = ps[tid];
      float sv[4] = {S0.x, S0.y, S0.z, S0.w};
      float wv[4];
#pragma unroll
      for (int j = 0; j < 4; ++j)
        wv[j] = g * __builtin_amdgcn_rcpf(fmaxf(2.f * __builtin_amdgcn_sqrtf(sv[j] * sc), EPS_MODEL));
      w2[c][0] = (v2f){wv[0], wv[1]};
      w2[c][1] = (v2f){wv[2], wv[3]};
    }

    // ================= type-1 sweeps =================
    for (int src = 0; src < NC; ++src) {
      v2f p2[12];
#pragma unroll
      for (int k = 0; k < 12; ++k) p2[k] = (v2f){0.f, 0.f};
#pragma unroll
      for (int h = 0; h < 2; ++h) {
        v2f xsr = xcr[src][h], xsi = xci[src][h];
        v2f msq = xsr * xsr + xsi * xsi;
#pragma unroll
        for (int c = 0; c < NC; ++c) {
          v2f wv = w2[c][h];
          p2[c]     += wv * (xcr[c][h] * xsr + xci[c][h] * xsi);
          p2[4 + c] += wv * (xci[c][h] * xsr - xcr[c][h] * xsi);
          p2[8 + c] += wv * msq;
        }
      }
      float p[12];
#pragma unroll
      for (int k = 0; k < 12; ++k) p[k] = p2[k].x + p2[k].y;
      float s12[12];
      block_reduce12(p, red, buf, lane, wvid, s12);
      buf ^= 1;

      float vr[NC], vi[NC];
#pragma unroll
      for (int c = 0; c < NC; ++c) {
        float den = fmaxf(s12[8 + c] * invN, EPSV);
        if (c == src) {
          vr[c] = 1.f - __builtin_amdgcn_rsqf(den);
          vi[c] = 0.f;
        } else {
          float sc = invN * __builtin_amdgcn_rcpf(den);
          vr[c] = s12[c] * sc;
          vi[c] = s12[4 + c] * sc;
        }
      }
#pragma unroll
      for (int h = 0; h < 2; ++h) {
        v2f xsr = xcr[src][h], xsi = xci[src][h];
#pragma unroll
        for (int c = 0; c < NC; ++c) {
          xcr[c][h] -= xsr * vr[c] - xsi * vi[c];
          xci[c][h] -= xsi * vr[c] + xsr * vi[c];
        }
      }
      if (tid == 0) {
#pragma unroll
        for (int jj = 0; jj < NC; ++jj) {
          float wsr = Wre[src][jj], wsi = Wim[src][jj];
#pragma unroll
          for (int c = 0; c < NC; ++c) {
            Wre[c][jj] -= vr[c] * wsr - vi[c] * wsi;
            Wim[c][jj] -= vr[c] * wsi + vi[c] * wsr;
          }
        }
      }
    }

    // ================= type-2 sweeps =================
    for (int src = 0; src < NC; ++src) {
      const float4* pr = reinterpret_cast<const float4*>(Xr + rowbase[src]);
      const float4* pi = reinterpret_cast<const float4*>(Xi + rowbase[src]);
      // 5-frame window [4t-3 .. 4t+1] of ORIGINAL X serves both taps
      // (tap semantics: Xst[tap, n] = X[n - 3 + tap]).
      float4 A4r = make_float4(0.f, 0.f, 0.f, 0.f), A4i = A4r;
      if (tid > 0) { A4r = pr[tid - 1]; A4i = pi[tid - 1]; }
      float4 B4r = pr[tid], B4i = pi[tid];
      float wr[5] = {A4r.y, A4r.z, A4r.w, B4r.x, B4r.y};
      float wi[5] = {A4i.y, A4i.z, A4i.w, B4i.x, B4i.y};
      for (int tap = 0; tap < 2; ++tap) {
        v2f xs_r[2], xs_i[2];
#pragma unroll
        for (int h = 0; h < 2; ++h) {
          xs_r[h] = (v2f){wr[tap + 2 * h], wr[tap + 2 * h + 1]};
          xs_i[h] = (v2f){wi[tap + 2 * h], wi[tap + 2 * h + 1]};
        }
        v2f p2[12];
#pragma unroll
        for (int k = 0; k < 12; ++k) p2[k] = (v2f){0.f, 0.f};
#pragma unroll
        for (int h = 0; h < 2; ++h) {
          v2f xsr = xs_r[h], xsi = xs_i[h];
          v2f msq = xsr * xsr + xsi * xsi;
#pragma unroll
          for (int c = 0; c < NC; ++c) {
            v2f wv = w2[c][h];
            p2[c]     += wv * (xcr[c][h] * xsr + xci[c][h] * xsi);
            p2[4 + c] += wv * (xci[c][h] * xsr - xcr[c][h] * xsi);
            p2[8 + c] += wv * msq;
          }
        }
        float p[12];
#pragma unroll
        for (int k = 0; k < 12; ++k) p[k] = p2[k].x + p2[k].y;
        float s12[12];
        block_reduce12(p, red, buf, lane, wvid, s12);
        buf ^= 1;

        float vr[NC], vi[NC];
#pragma unroll
        for (int c = 0; c < NC; ++c) {
          float den = fmaxf(s12[8 + c], EPSV);  // SUM, not mean
          float sc = invN * __builtin_amdgcn_rcpf(den);
          vr[c] = s12[c] * sc;
          vi[c] = s12[4 + c] * sc;
        }
#pragma unroll
        for (int h = 0; h < 2; ++h) {
          v2f xsr = xs_r[h], xsi = xs_i[h];
#pragma unroll
          for (int c = 0; c < NC; ++c) {
            xcr[c][h] -= xsr * vr[c] - xsi * vi[c];
            xci[c][h] -= xsi * vr[c] + xsr * vi[c];
          }
        }
      }
    }
  }  // epochs

  // ---- solve W^T a = e1 (4x4 complex, partial pivoting), A[i][j] = W[j][i] ----
  __syncthreads();
  if (tid == 0) {
    float Ar[4][4], Ai[4][4];
    float br[4] = {1.f, 0.f, 0.f, 0.f}, bi[4] = {0.f, 0.f, 0.f, 0.f};
#pragma unroll
    for (int i = 0; i < 4; ++i)
#pragma unroll
      for (int j = 0; j < 4; ++j) {
        Ar[i][j] = Wre[j][i];
        Ai[i][j] = Wim[j][i];
      }
    for (int k = 0; k < 4; ++k) {
      int piv = k;
      float best = Ar[k][k] * Ar[k][k] + Ai[k][k] * Ai[k][k];
      for (int i = k + 1; i < 4; ++i) {
        float m = Ar[i][k] * Ar[i][k] + Ai[i][k] * Ai[i][k];
        if (m > best) { best = m; piv = i; }
      }
      if (piv != k) {
        for (int j = 0; j < 4; ++j) {
          float t = Ar[k][j]; Ar[k][j] = Ar[piv][j]; Ar[piv][j] = t;
          t = Ai[k][j]; Ai[k][j] = Ai[piv][j]; Ai[piv][j] = t;
        }
        float t = br[k]; br[k] = br[piv]; br[piv] = t;
        t = bi[k]; bi[k] = bi[piv]; bi[piv] = t;
      }
      float dr = Ar[k][k], di = Ai[k][k];
      float inv = 1.f / (dr * dr + di * di);
      for (int i = k + 1; i < 4; ++i) {
        float fr = (Ar[i][k] * dr + Ai[i][k] * di) * inv;
        float fi = (Ai[i][k] * dr - Ar[i][k] * di) * inv;
        for (int j = k; j < 4; ++j) {
          Ar[i][j] -= fr * Ar[k][j] - fi * Ai[k][j];
          Ai[i][j] -= fr * Ai[k][j] + fi * Ar[k][j];
        }
        br[i] -= fr * br[k] - fi * bi[k];
        bi[i] -= fr * bi[k] + fi * br[k];
      }
    }
    float ar[4], ai[4];
    for (int k = 3; k >= 0; --k) {
      float sr = br[k], si = bi[k];
      for (int j = k + 1; j < 4; ++j) {
        sr -= Ar[k][j] * ar[j] - Ai[k][j] * ai[j];
        si -= Ar[k][j] * ai[j] + Ai[k][j] * ar[j];
      }
      float dr = Ar[k][k], di = Ai[k][k];
      float inv = 1.f / (dr * dr + di * di);
      ar[k] = (sr * dr + si * di) * inv;
      ai[k] = (si * dr - sr * di) * inv;
    }
#pragma unroll
    for (int c = 0; c < 4; ++c) { abc[c] = ar[c]; abc[4 + c] = ai[c]; }
  }
  __syncthreads();

  // ---- output: real(Xc * a), 1x float4 per (c, thread), bounds-guarded ----
#pragma unroll
  for (int c = 0; c < NC; ++c) {
    float ar = abc[c], ai2 = abc[4 + c];
    if (rowbase[c] + 4 * tid + 3 < nout) {
      float4* po = reinterpret_cast<float4*>(out + rowbase[c]);
      v2f o0 = xcr[c][0] * ar - xci[c][0] * ai2;
      v2f o1 = xcr[c][1] * ar - xci[c][1] * ai2;
      po[tid] = make_float4(o0.x, o0.y, o1.x, o1.y);
    }
  }
}

// ---------------------------------------------------------------------------
extern "C" void kernel_launch(void* const* d_in, const int* in_sizes, int n_in,
                              void* d_out, int out_size, void* d_ws, size_t ws_size,
                              hipStream_t stream) {
  const float* Xr = (const float*)d_in[0];
  const float* Xi = (const float*)d_in[1];
  float* out = (float*)d_out;

  dim3 g1(16, NCHUNK);
  k_colsum<<<g1, 256, 0, stream>>>(Xr, Xi);
  k_redgp<<<16, 256, 0, stream>>>();
  k_main<<<NB * NF, 256, 0, stream>>>(Xr, Xi, out, out_size);
}

// Round 2
// 221.953 us; speedup vs baseline: 1.1223x; 1.1223x over previous
//
#include <hip/hip_runtime.h>
#include <math.h>

#define NB 4
#define NC 4
#define NF 257
#define NFR 1024
#define NTOT (NB * NC * NF * NFR)
#define NBC (NB * NC)
#define EPSV 1e-3f
#define EPS_MODEL 1e-5f
#define NCHUNK 32

typedef float v2f __attribute__((ext_vector_type(2)));

// Module-scope scratch: allocated at load, graph-capture safe, fully
// rewritten every call.
__device__ float g_Spart[NCHUNK * NBC * NFR];  // partial column sums
__device__ float g_S[NBC * NFR];               // S[b,c,n] = sum_f |X[b,c,f,n]|^2
__device__ float g_gP[96];                     // g_e, P_e per (b,c), e=0..2

// Wave-wide sum via DPP (VALU pipe, no LDS traffic). Lane 63 holds the sum.
__device__ __forceinline__ float dpp_red_sum(float v) {
  v += __int_as_float(__builtin_amdgcn_update_dpp(0, __float_as_int(v), 0x111, 0xf, 0xf, true)); // row_shr:1
  v += __int_as_float(__builtin_amdgcn_update_dpp(0, __float_as_int(v), 0x112, 0xf, 0xf, true)); // row_shr:2
  v += __int_as_float(__builtin_amdgcn_update_dpp(0, __float_as_int(v), 0x114, 0xf, 0xf, true)); // row_shr:4
  v += __int_as_float(__builtin_amdgcn_update_dpp(0, __float_as_int(v), 0x118, 0xf, 0xf, true)); // row_shr:8
  v += __int_as_float(__builtin_amdgcn_update_dpp(0, __float_as_int(v), 0x142, 0xa, 0xf, true)); // row_bcast:15
  v += __int_as_float(__builtin_amdgcn_update_dpp(0, __float_as_int(v), 0x143, 0xc, 0xf, true)); // row_bcast:31
  return v;
}

// ---------------------------------------------------------------------------
// K1: partial column sums, float4-vectorized, 512 blocks (full GPU).
// ---------------------------------------------------------------------------
__global__ __launch_bounds__(256) void k_colsum(const float* __restrict__ Xr,
                                                const float* __restrict__ Xi) {
  int u = blockIdx.x * 256 + threadIdx.x;  // bc*256 + q
  int fc = blockIdx.y;
  int f0 = fc * 9;
  int f1 = f0 + 9; if (f1 > NF) f1 = NF;
  int bc = u >> 8, q = u & 255;
  float4 s = make_float4(0.f, 0.f, 0.f, 0.f);
  for (int f = f0; f < f1; ++f) {
    float4 a = reinterpret_cast<const float4*>(Xr + (bc * NF + f) * NFR)[q];
    float4 b = reinterpret_cast<const float4*>(Xi + (bc * NF + f) * NFR)[q];
    s.x += a.x * a.x + b.x * b.x;
    s.y += a.y * a.y + b.y * b.y;
    s.z += a.z * a.z + b.z * b.z;
    s.w += a.w * a.w + b.w * b.w;
  }
  reinterpret_cast<float4*>(g_Spart + fc * (NBC * NFR) + bc * NFR)[q] = s;
}

// ---------------------------------------------------------------------------
// K2 (fused): reduce 32 partials -> g_S; block-reduce to s0; g_e/P_e table.
// ---------------------------------------------------------------------------
__global__ __launch_bounds__(256) void k_redgp() {
  int bc = blockIdx.x, tid = threadIdx.x;
  float4 s = make_float4(0.f, 0.f, 0.f, 0.f);
#pragma unroll
  for (int fc = 0; fc < NCHUNK; ++fc) {
    float4 a = reinterpret_cast<const float4*>(g_Spart + fc * (NBC * NFR) + bc * NFR)[tid];
    s.x += a.x; s.y += a.y; s.z += a.z; s.w += a.w;
  }
  reinterpret_cast<float4*>(g_S + bc * NFR)[tid] = s;
  float p = dpp_red_sum(s.x + s.y + s.z + s.w);
  __shared__ float r[4];
  if ((tid & 63) == 63) r[tid >> 6] = p;
  __syncthreads();
  if (tid == 0) {
    float s0 = (r[0] + r[1] + r[2] + r[3]) / (float)(NF * NFR);
    float P = 1.f;
#pragma unroll
    for (int e = 0; e < 3; ++e) {
      float g = fmaxf(s0 / P, 1e-5f);
      g_gP[e * 32 + bc] = g;
      g_gP[e * 32 + 16 + bc] = P;
      P *= g;
    }
  }
}

// Block-level reduction of 12 partials, 4-wave version: DPP within wave,
// one barrier, b128 LDS round-trip, double-buffered via `buf`.
__device__ __forceinline__ void block_reduce12(float* __restrict__ p,
                                               float (*red)[4][12], int buf,
                                               int lane, int wvid,
                                               float* __restrict__ s) {
#pragma unroll
  for (int k = 0; k < 12; ++k) p[k] = dpp_red_sum(p[k]);
  if (lane == 63) {
    float4* dst = reinterpret_cast<float4*>(&red[buf][wvid][0]);
    dst[0] = make_float4(p[0], p[1], p[2], p[3]);
    dst[1] = make_float4(p[4], p[5], p[6], p[7]);
    dst[2] = make_float4(p[8], p[9], p[10], p[11]);
  }
  __syncthreads();
  const float4* r = reinterpret_cast<const float4*>(&red[buf][0][0]);
#pragma unroll
  for (int k = 0; k < 3; ++k) {
    float4 a = r[k], b = r[3 + k], c = r[6 + k], d = r[9 + k];
    s[4 * k + 0] = a.x + b.x + c.x + d.x;
    s[4 * k + 1] = a.y + b.y + c.y + d.y;
    s[4 * k + 2] = a.z + b.z + c.z + d.z;
    s[4 * k + 3] = a.w + b.w + c.w + d.w;
  }
}

// ---------------------------------------------------------------------------
// Main: one block per (b,f), 256 threads (4 waves), 4 frames/thread held as
// 2x v2f (<2 x float>) pairs -> v_pk_fma_f32 codegen for accumulate/update.
// 4 waves/block raises resident waves/CU (grid fixed at 1028 blocks):
// latency hiding for the 36 serial DPP+barrier sweep stages.
// (256,2) bounds: VGPR cap 256 — round 1's (256,4) cap of 128 forced ~400 B
// of scratch spill per thread (WRITE_SIZE 16->117 MB), a 6x HBM-traffic
// regression. Actual usage ~100 VGPR still lands in the 4-waves/SIMD bucket,
// so occupancy is unchanged vs (256,4) but with zero spill traffic.
// ---------------------------------------------------------------------------
__global__ __launch_bounds__(256, 2) void k_main(const float* __restrict__ Xr,
                                                 const float* __restrict__ Xi,
                                                 float* __restrict__ out, int nout) {
  const int blk = blockIdx.x;
  const int b = blk / NF, f = blk % NF;
  const int tid = threadIdx.x;            // 0..255
  const int lane = tid & 63, wvid = tid >> 6;
  const float invN = 1.f / (float)NFR;

  __shared__ float red[2][4][12];
  __shared__ float Wre[NC][NC], Wim[NC][NC];
  __shared__ float abc[8];

  v2f xcr[NC][2], xci[NC][2];
  int rowbase[NC];
#pragma unroll
  for (int c = 0; c < NC; ++c) {
    rowbase[c] = ((b * NC + c) * NF + f) * NFR;
    const float4* pr = reinterpret_cast<const float4*>(Xr + rowbase[c]);
    const float4* pi = reinterpret_cast<const float4*>(Xi + rowbase[c]);
    float4 a0 = pr[tid];
    float4 b0 = pi[tid];
    xcr[c][0] = (v2f){a0.x, a0.y}; xcr[c][1] = (v2f){a0.z, a0.w};
    xci[c][0] = (v2f){b0.x, b0.y}; xci[c][1] = (v2f){b0.z, b0.w};
  }
  if (tid < 16) {
    Wre[tid >> 2][tid & 3] = ((tid >> 2) == (tid & 3)) ? 1.f : 0.f;
    Wim[tid >> 2][tid & 3] = 0.f;
  }
  // W-init visibility to thread 0: ordered by the first sweep's barrier.

  v2f w2[NC][2];
  int buf = 0;

  for (int e = 0; e < 3; ++e) {
    // ---- per-epoch weights: w = g * rcp(max(2*sqrt(S/P), eps)) ----
#pragma unroll
    for (int c = 0; c < NC; ++c) {
      float g = g_gP[e * 32 + b * NC + c];
      float P = g_gP[e * 32 + 16 + b * NC + c];
      float sc = __builtin_amdgcn_rcpf(P);
      const float4* ps = reinterpret_cast<const float4*>(g_S + (b * NC + c) * NFR);
      float4 S0 = ps[tid];
      float sv[4] = {S0.x, S0.y, S0.z, S0.w};
      float wv[4];
#pragma unroll
      for (int j = 0; j < 4; ++j)
        wv[j] = g * __builtin_amdgcn_rcpf(fmaxf(2.f * __builtin_amdgcn_sqrtf(sv[j] * sc), EPS_MODEL));
      w2[c][0] = (v2f){wv[0], wv[1]};
      w2[c][1] = (v2f){wv[2], wv[3]};
    }

    // ================= type-1 sweeps =================
    for (int src = 0; src < NC; ++src) {
      v2f p2[12];
#pragma unroll
      for (int k = 0; k < 12; ++k) p2[k] = (v2f){0.f, 0.f};
#pragma unroll
      for (int h = 0; h < 2; ++h) {
        v2f xsr = xcr[src][h], xsi = xci[src][h];
        v2f msq = xsr * xsr + xsi * xsi;
#pragma unroll
        for (int c = 0; c < NC; ++c) {
          v2f wv = w2[c][h];
          p2[c]     += wv * (xcr[c][h] * xsr + xci[c][h] * xsi);
          p2[4 + c] += wv * (xci[c][h] * xsr - xcr[c][h] * xsi);
          p2[8 + c] += wv * msq;
        }
      }
      float p[12];
#pragma unroll
      for (int k = 0; k < 12; ++k) p[k] = p2[k].x + p2[k].y;
      float s12[12];
      block_reduce12(p, red, buf, lane, wvid, s12);
      buf ^= 1;

      float vr[NC], vi[NC];
#pragma unroll
      for (int c = 0; c < NC; ++c) {
        float den = fmaxf(s12[8 + c] * invN, EPSV);
        if (c == src) {
          vr[c] = 1.f - __builtin_amdgcn_rsqf(den);
          vi[c] = 0.f;
        } else {
          float sc = invN * __builtin_amdgcn_rcpf(den);
          vr[c] = s12[c] * sc;
          vi[c] = s12[4 + c] * sc;
        }
      }
#pragma unroll
      for (int h = 0; h < 2; ++h) {
        v2f xsr = xcr[src][h], xsi = xci[src][h];
#pragma unroll
        for (int c = 0; c < NC; ++c) {
          xcr[c][h] -= xsr * vr[c] - xsi * vi[c];
          xci[c][h] -= xsi * vr[c] + xsr * vi[c];
        }
      }
      if (tid == 0) {
#pragma unroll
        for (int jj = 0; jj < NC; ++jj) {
          float wsr = Wre[src][jj], wsi = Wim[src][jj];
#pragma unroll
          for (int c = 0; c < NC; ++c) {
            Wre[c][jj] -= vr[c] * wsr - vi[c] * wsi;
            Wim[c][jj] -= vr[c] * wsi + vi[c] * wsr;
          }
        }
      }
    }

    // ================= type-2 sweeps =================
    for (int src = 0; src < NC; ++src) {
      const float4* pr = reinterpret_cast<const float4*>(Xr + rowbase[src]);
      const float4* pi = reinterpret_cast<const float4*>(Xi + rowbase[src]);
      // 5-frame window [4t-3 .. 4t+1] of ORIGINAL X serves both taps
      // (tap semantics: Xst[tap, n] = X[n - 3 + tap]).
      float4 A4r = make_float4(0.f, 0.f, 0.f, 0.f), A4i = A4r;
      if (tid > 0) { A4r = pr[tid - 1]; A4i = pi[tid - 1]; }
      float4 B4r = pr[tid], B4i = pi[tid];
      float wr[5] = {A4r.y, A4r.z, A4r.w, B4r.x, B4r.y};
      float wi[5] = {A4i.y, A4i.z, A4i.w, B4i.x, B4i.y};
      // tap loop MUST be fully unrolled: runtime tap would make wr/wi
      // runtime-indexed -> scratch demotion (rule #20).
#pragma unroll
      for (int tap = 0; tap < 2; ++tap) {
        v2f xs_r[2], xs_i[2];
#pragma unroll
        for (int h = 0; h < 2; ++h) {
          xs_r[h] = (v2f){wr[tap + 2 * h], wr[tap + 2 * h + 1]};
          xs_i[h] = (v2f){wi[tap + 2 * h], wi[tap + 2 * h + 1]};
        }
        v2f p2[12];
#pragma unroll
        for (int k = 0; k < 12; ++k) p2[k] = (v2f){0.f, 0.f};
#pragma unroll
        for (int h = 0; h < 2; ++h) {
          v2f xsr = xs_r[h], xsi = xs_i[h];
          v2f msq = xsr * xsr + xsi * xsi;
#pragma unroll
          for (int c = 0; c < NC; ++c) {
            v2f wv = w2[c][h];
            p2[c]     += wv * (xcr[c][h] * xsr + xci[c][h] * xsi);
            p2[4 + c] += wv * (xci[c][h] * xsr - xcr[c][h] * xsi);
            p2[8 + c] += wv * msq;
          }
        }
        float p[12];
#pragma unroll
        for (int k = 0; k < 12; ++k) p[k] = p2[k].x + p2[k].y;
        float s12[12];
        block_reduce12(p, red, buf, lane, wvid, s12);
        buf ^= 1;

        float vr[NC], vi[NC];
#pragma unroll
        for (int c = 0; c < NC; ++c) {
          float den = fmaxf(s12[8 + c], EPSV);  // SUM, not mean
          float sc = invN * __builtin_amdgcn_rcpf(den);
          vr[c] = s12[c] * sc;
          vi[c] = s12[4 + c] * sc;
        }
#pragma unroll
        for (int h = 0; h < 2; ++h) {
          v2f xsr = xs_r[h], xsi = xs_i[h];
#pragma unroll
          for (int c = 0; c < NC; ++c) {
            xcr[c][h] -= xsr * vr[c] - xsi * vi[c];
            xci[c][h] -= xsi * vr[c] + xsr * vi[c];
          }
        }
      }
    }
  }  // epochs

  // ---- solve W^T a = e1 (4x4 complex, partial pivoting), A[i][j] = W[j][i] ----
  __syncthreads();
  if (tid == 0) {
    float Ar[4][4], Ai[4][4];
    float br[4] = {1.f, 0.f, 0.f, 0.f}, bi[4] = {0.f, 0.f, 0.f, 0.f};
#pragma unroll
    for (int i = 0; i < 4; ++i)
#pragma unroll
      for (int j = 0; j < 4; ++j) {
        Ar[i][j] = Wre[j][i];
        Ai[i][j] = Wim[j][i];
      }
    for (int k = 0; k < 4; ++k) {
      int piv = k;
      float best = Ar[k][k] * Ar[k][k] + Ai[k][k] * Ai[k][k];
      for (int i = k + 1; i < 4; ++i) {
        float m = Ar[i][k] * Ar[i][k] + Ai[i][k] * Ai[i][k];
        if (m > best) { best = m; piv = i; }
      }
      if (piv != k) {
        for (int j = 0; j < 4; ++j) {
          float t = Ar[k][j]; Ar[k][j] = Ar[piv][j]; Ar[piv][j] = t;
          t = Ai[k][j]; Ai[k][j] = Ai[piv][j]; Ai[piv][j] = t;
        }
        float t = br[k]; br[k] = br[piv]; br[piv] = t;
        t = bi[k]; bi[k] = bi[piv]; bi[piv] = t;
      }
      float dr = Ar[k][k], di = Ai[k][k];
      float inv = 1.f / (dr * dr + di * di);
      for (int i = k + 1; i < 4; ++i) {
        float fr = (Ar[i][k] * dr + Ai[i][k] * di) * inv;
        float fi = (Ai[i][k] * dr - Ar[i][k] * di) * inv;
        for (int j = k; j < 4; ++j) {
          Ar[i][j] -= fr * Ar[k][j] - fi * Ai[k][j];
          Ai[i][j] -= fr * Ai[k][j] + fi * Ar[k][j];
        }
        br[i] -= fr * br[k] - fi * bi[k];
        bi[i] -= fr * bi[k] + fi * br[k];
      }
    }
    float ar[4], ai[4];
    for (int k = 3; k >= 0; --k) {
      float sr = br[k], si = bi[k];
      for (int j = k + 1; j < 4; ++j) {
        sr -= Ar[k][j] * ar[j] - Ai[k][j] * ai[j];
        si -= Ar[k][j] * ai[j] + Ai[k][j] * ar[j];
      }
      float dr = Ar[k][k], di = Ai[k][k];
      float inv = 1.f / (dr * dr + di * di);
      ar[k] = (sr * dr + si * di) * inv;
      ai[k] = (si * dr - sr * di) * inv;
    }
#pragma unroll
    for (int c = 0; c < 4; ++c) { abc[c] = ar[c]; abc[4 + c] = ai[c]; }
  }
  __syncthreads();

  // ---- output: real(Xc * a), 1x float4 per (c, thread), bounds-guarded ----
#pragma unroll
  for (int c = 0; c < NC; ++c) {
    float ar = abc[c], ai2 = abc[4 + c];
    if (rowbase[c] + 4 * tid + 3 < nout) {
      float4* po = reinterpret_cast<float4*>(out + rowbase[c]);
      v2f o0 = xcr[c][0] * ar - xci[c][0] * ai2;
      v2f o1 = xcr[c][1] * ar - xci[c][1] * ai2;
      po[tid] = make_float4(o0.x, o0.y, o1.x, o1.y);
    }
  }
}

// ---------------------------------------------------------------------------
extern "C" void kernel_launch(void* const* d_in, const int* in_sizes, int n_in,
                              void* d_out, int out_size, void* d_ws, size_t ws_size,
                              hipStream_t stream) {
  const float* Xr = (const float*)d_in[0];
  const float* Xi = (const float*)d_in[1];
  float* out = (float*)d_out;

  dim3 g1(16, NCHUNK);
  k_colsum<<<g1, 256, 0, stream>>>(Xr, Xi);
  k_redgp<<<16, 256, 0, stream>>>();
  k_main<<<NB * NF, 256, 0, stream>>>(Xr, Xi, out, out_size);
}